// Round 3
// baseline (697.642 us; speedup 1.0000x reference)
//
#include <hip/hip_runtime.h>
#include <math.h>

#define Bsz 4
#define Nn  4096
#define Dd  64
#define TOT (Bsz*Nn*Dd)          // 1048576
#define GRID 512

typedef unsigned int u32;
typedef unsigned long long u64;
typedef short short8 __attribute__((ext_vector_type(8)));
typedef float f32x4 __attribute__((ext_vector_type(4)));

// ---------------- helpers ----------------
__device__ __forceinline__ unsigned short bf16_of(float x) {
  u32 u = __float_as_uint(x);
  u32 r = (u + 0x7FFFu + ((u >> 16) & 1u)) >> 16;   // RNE
  return (unsigned short)r;
}
__device__ __forceinline__ u32 pack2(float a, float b) {
  return (u32)bf16_of(a) | ((u32)bf16_of(b) << 16);
}
__device__ __forceinline__ void gll16(const void* g, void* l) {
  __builtin_amdgcn_global_load_lds((const __attribute__((address_space(1))) void*)g,
                                   (__attribute__((address_space(3))) void*)l, 16, 0, 0);
}

// Threefry-2x32 (exact JAX rotation/key schedule)
__device__ __forceinline__ void tf(u32 k0, u32 k1, u32 x0, u32 x1, u32& y0, u32& y1) {
  u32 ks2 = k0 ^ k1 ^ 0x1BD11BDAu;
  x0 += k0; x1 += k1;
#define TFR(r) { x0 += x1; x1 = (x1 << (r)) | (x1 >> (32 - (r))); x1 ^= x0; }
  TFR(13) TFR(15) TFR(26) TFR(6)
  x0 += k1; x1 += ks2 + 1u;
  TFR(17) TFR(29) TFR(16) TFR(24)
  x0 += ks2; x1 += k0 + 2u;
  TFR(13) TFR(15) TFR(26) TFR(6)
  x0 += k0; x1 += k1 + 3u;
  TFR(17) TFR(29) TFR(16) TFR(24)
  x0 += k1; x1 += ks2 + 4u;
  TFR(13) TFR(15) TFR(26) TFR(6)
  x0 += ks2; x1 += k0 + 5u;
#undef TFR
  y0 = x0; y1 = x1;
}

// bit->bf16 expansion (tau-compensated, verified R1/R2)
__device__ __forceinline__ short8 expand_byte(u32 byte) {
  u32 lo = byte & 15u, hi = (byte >> 4) & 15u;
  u32 s0 = (lo * 0x00204081u) & 0x01010101u;
  u32 s1 = (hi * 0x00204081u) & 0x01010101u;
  union { u32 u[4]; short8 v; } r;
  r.u[0] = (s0 & 0x00010001u) * 0x3F80u;
  r.u[1] = ((s0 >> 8) & 0x00010001u) * 0x3F80u;
  r.u[2] = (s1 & 0x00010001u) * 0x3F80u;
  r.u[3] = ((s1 >> 8) & 0x00010001u) * 0x3F80u;
  return r.v;
}

// ---------------- shared memory union (max ~33.8 KB -> 4 blocks/CU possible, need 2) ----
union SMem {
  struct { unsigned short Xl[32][72]; unsigned short Wt[64][72]; float dl[32]; } xw;
  struct { unsigned short Zt[64 * 256]; u64 Bl[32][4]; } sp;   // 32768 + 1024 B
  struct { int cnt[32][4]; } bt;
};

// ---------------- device-scope grid barrier (counters zeroed by k_init) ----
__device__ __forceinline__ void gridbar(u32* c) {
  __syncthreads();
  if (threadIdx.x == 0) {
    __builtin_amdgcn_fence(__ATOMIC_RELEASE, "agent");
    __hip_atomic_fetch_add(c, 1u, __ATOMIC_RELAXED, __HIP_MEMORY_SCOPE_AGENT);
    while (__hip_atomic_load(c, __ATOMIC_RELAXED, __HIP_MEMORY_SCOPE_AGENT) < (u32)GRID)
      __builtin_amdgcn_s_sleep(2);
    __builtin_amdgcn_fence(__ATOMIC_ACQUIRE, "agent");
  }
  __syncthreads();
}

// ---------------- phase: adj -> bits + dinv (32 rows/block) ----------------
__device__ void ph_bits(const int* __restrict__ adj, u64* __restrict__ bits,
                        float* __restrict__ dinv, int blk, SMem& sm) {
  int tid = threadIdx.x, lane = tid & 63, wv = tid >> 6;
  int gr0 = blk * 32;
  for (int r = 0; r < 32; ++r) {
    int row = gr0 + r;
    int i = row & (Nn - 1);
    const int4* rp = (const int4*)(adj + (size_t)row * Nn + tid * 16);
    int4 a0 = rp[0], a1 = rp[1], a2 = rp[2], a3 = rp[3];
    u32 v = 0;
    v |= (a0.x != 0) ? (1u << 0) : 0u;  v |= (a0.y != 0) ? (1u << 2) : 0u;
    v |= (a0.z != 0) ? (1u << 1) : 0u;  v |= (a0.w != 0) ? (1u << 3) : 0u;
    v |= (a1.x != 0) ? (1u << 4) : 0u;  v |= (a1.y != 0) ? (1u << 6) : 0u;
    v |= (a1.z != 0) ? (1u << 5) : 0u;  v |= (a1.w != 0) ? (1u << 7) : 0u;
    v |= (a2.x != 0) ? (1u << 8) : 0u;  v |= (a2.y != 0) ? (1u << 10) : 0u;
    v |= (a2.z != 0) ? (1u << 9) : 0u;  v |= (a2.w != 0) ? (1u << 11) : 0u;
    v |= (a3.x != 0) ? (1u << 12) : 0u; v |= (a3.y != 0) ? (1u << 14) : 0u;
    v |= (a3.z != 0) ? (1u << 13) : 0u; v |= (a3.w != 0) ? (1u << 15) : 0u;
    if ((i >> 4) == tid) {              // self-loop column in my 16
      int e = i & 15, e7 = e & 7;
      int m = ((e7 ^ (e7 >> 1)) & 1);
      v |= 1u << ((e & 8) + (e7 ^ (m * 3)));
    }
    ((unsigned short*)bits)[(size_t)row * 256 + tid] = (unsigned short)v;
    int c = __popc(v);
    c += __shfl_down(c, 32, 64); c += __shfl_down(c, 16, 64);
    c += __shfl_down(c, 8, 64);  c += __shfl_down(c, 4, 64);
    c += __shfl_down(c, 2, 64);  c += __shfl_down(c, 1, 64);
    if (lane == 0) sm.bt.cnt[r][wv] = c;
  }
  __syncthreads();
  if (tid < 32) {
    int deg = sm.bt.cnt[tid][0] + sm.bt.cnt[tid][1] + sm.bt.cnt[tid][2] + sm.bt.cnt[tid][3];
    dinv[gr0 + tid] = (float)(1.0 / sqrt((double)deg));
  }
}

// ---------------- phase: dropout masks (4 KB/block, exact JAX threefry) ------
__device__ void ph_masks(unsigned char* __restrict__ masks, int blk) {
  u32 k1a, k1b, k2a, k2b;
  tf(0u, 42u, 0u, 0u, k1a, k1b);
  tf(0u, 42u, 0u, 1u, k2a, k2b);
  int base = blk * 4096 + threadIdx.x * 16;     // covers [0, 2*TOT)
  u32 res[4];
#pragma unroll
  for (int w = 0; w < 4; ++w) {
    u32 acc = 0;
#pragma unroll
    for (int j = 0; j < 4; ++j) {
      int g = base + w * 4 + j;
      int layer = g >> 20;
      u32 f = (u32)(g & (TOT - 1));
      u32 h0, h1; tf(layer ? k2a : k1a, layer ? k2b : k1b, 0u, f, h0, h1);
      u32 bv = h0 ^ h1;
      float u = __uint_as_float((bv >> 9) | 0x3F800000u) - 1.0f;
      acc |= (u < 0.8f ? 1u : 0u) << (8 * j);
    }
    res[w] = acc;
  }
  uint4 st; st.x = res[0]; st.y = res[1]; st.z = res[2]; st.w = res[3];
  *(uint4*)(masks + base) = st;
}

// ---------------- phase: Yt = swizzled-T( dinv .* (src @ W) ), 32 rows/block --
__device__ void ph_xw(const float* __restrict__ src, const float* __restrict__ W,
                      const float* __restrict__ dinv, unsigned short* __restrict__ Yt,
                      int blk, SMem& sm) {
  int tid = threadIdx.x;
  int gr0 = blk * 32;
#pragma unroll
  for (int it = 0; it < 4; ++it) {
    int p = it * 256 + tid;
    int r = p >> 5, c2 = (p & 31) * 2;
    const float* s2 = src + (size_t)(gr0 + r) * Dd + c2;
    *(u32*)&sm.xw.Xl[r][c2] = pack2(s2[0], s2[1]);
  }
#pragma unroll
  for (int it = 0; it < 16; ++it) {
    int e = it * 256 + tid;
    int k = e >> 6, d = e & 63;
    sm.xw.Wt[d][k] = bf16_of(W[e]);
  }
  if (tid < 32) sm.xw.dl[tid] = dinv[gr0 + tid];
  __syncthreads();

  int lane = tid & 63, wv = tid >> 6, q = lane >> 4, ln = lane & 15;
  int s = wv & 1, tp = wv >> 1;
  f32x4 acc[2];
#pragma unroll
  for (int tt = 0; tt < 2; ++tt) { acc[tt][0]=0.f; acc[tt][1]=0.f; acc[tt][2]=0.f; acc[tt][3]=0.f; }
#pragma unroll
  for (int ks = 0; ks < 2; ++ks) {
    short8 a = *(short8*)&sm.xw.Xl[s * 16 + ln][ks * 32 + q * 8];
#pragma unroll
    for (int tt = 0; tt < 2; ++tt) {
      short8 bfr = *(short8*)&sm.xw.Wt[(tp * 2 + tt) * 16 + ln][ks * 32 + q * 8];
      acc[tt] = __builtin_amdgcn_mfma_f32_16x16x32_bf16(a, bfr, acc[tt], 0, 0, 0);
    }
  }
  int b = gr0 >> 12, i_in_b = gr0 & (Nn - 1);
#pragma unroll
  for (int tt = 0; tt < 2; ++tt) {
    int d = (tp * 2 + tt) * 16 + ln;
    int j0 = i_in_b + s * 16 + q * 4;
    unsigned short h[4];
#pragma unroll
    for (int r = 0; r < 4; ++r) h[r] = bf16_of(acc[tt][r] * sm.xw.dl[s * 16 + q * 4 + r]);
    int byte0 = (2 * j0) & 511, blk2 = (2 * j0) >> 9;
    size_t off = ((size_t)b * 64 + d) * (Nn * 2) + ((size_t)blk2 << 9)
               + (size_t)(byte0 ^ ((d & 7) << 4));
    uint2 st; st.x = (u32)h[0] | ((u32)h[1] << 16); st.y = (u32)h[2] | ((u32)h[3] << 16);
    *(uint2*)((char*)Yt + off) = st;
  }
}

// ---------------- phase: dst = epi( dinv .* (A_bin @ Yt) + bias ), 32 rows ----
__device__ void ph_spmm(const u64* __restrict__ bits, const unsigned short* __restrict__ Yt,
                        const float* __restrict__ dinv, const float* __restrict__ bias,
                        const unsigned char* __restrict__ mask, float* __restrict__ dst,
                        int blk, int act, SMem& sm) {
  int tid = threadIdx.x, lane = tid & 63, wv = tid >> 6, q = lane >> 4, ln = lane & 15;
  int gr0 = blk * 32;
  int b = gr0 >> 12, i0 = gr0 & (Nn - 1);
  int s = wv & 1, tp = wv >> 1;
  f32x4 acc[2];
#pragma unroll
  for (int tt = 0; tt < 2; ++tt) { acc[tt][0]=0.f; acc[tt][1]=0.f; acc[tt][2]=0.f; acc[tt][3]=0.f; }

  const char* ytp = (const char*)Yt + (size_t)b * 64 * (Nn * 2);
  const char* btp = (const char*)bits + ((size_t)b * Nn + i0) * 512;

  for (int it = 0; it < 16; ++it) {
    __syncthreads();                    // protect LDS from prev-iter readers
#pragma unroll
    for (int qq = 0; qq < 8; ++qq) {    // Zt: 32 KB (full d, K-slice of 256)
      int c = wv * 8 + qq;
      int d = c * 2 + (lane >> 5);
      const char* g = ytp + (size_t)d * (Nn * 2) + ((size_t)it << 9) + (size_t)(lane & 31) * 16;
      gll16(g, (char*)sm.sp.Zt + (size_t)c * 1024);
    }
    if (wv == 0) {                      // bits: 1 KB (32 rows x 32 B)
      const char* g = btp + (size_t)(lane >> 1) * 512 + (size_t)it * 32 + (size_t)(lane & 1) * 16;
      gll16(g, (char*)sm.sp.Bl);
    }
    __builtin_amdgcn_s_waitcnt(0);
    __syncthreads();

    u64 wd = 0;
#pragma unroll
    for (int kk = 0; kk < 8; ++kk) {
      if ((kk & 1) == 0) wd = sm.sp.Bl[s * 16 + ln][kk >> 1];
      u32 byte = (u32)(wd >> (8 * (4 * (kk & 1) + q))) & 0xFFu;
      short8 af = expand_byte(byte);
#pragma unroll
      for (int tt = 0; tt < 2; ++tt) {
        int d = (tp * 2 + tt) * 16 + ln;
        int off = ((kk * 64 + q * 16) ^ ((d & 7) << 4)) + d * 512;
        short8 bfr = *(short8*)((char*)sm.sp.Zt + off);
        acc[tt] = __builtin_amdgcn_mfma_f32_16x16x32_bf16(af, bfr, acc[tt], 0, 0, 0);
      }
    }
  }
  // fused epilogue
#pragma unroll
  for (int tt = 0; tt < 2; ++tt) {
    int d = (tp * 2 + tt) * 16 + ln;
    float bv = bias[d];
#pragma unroll
    for (int r = 0; r < 4; ++r) {
      int grow = gr0 + s * 16 + q * 4 + r;
      float v = acc[tt][r] * dinv[grow] + bv;
      if (act) {
        float e = v > 0.f ? v : expm1f(v);
        v = mask[(size_t)grow * 64 + d] ? e * 1.25f : 0.f;   // /0.8 == *1.25
      }
      dst[(size_t)grow * 64 + d] = v;
    }
  }
}

// ---------------- kernels ----------------
__global__ void k_init(u32* ctr) {
  if (threadIdx.x < 8)
    __hip_atomic_store(&ctr[threadIdx.x], 0u, __ATOMIC_RELAXED, __HIP_MEMORY_SCOPE_AGENT);
}

__global__ __launch_bounds__(256, 2) void k_fused(
    const float* __restrict__ x, const int* __restrict__ adj,
    const float* __restrict__ W1, const float* __restrict__ b1,
    const float* __restrict__ W2, const float* __restrict__ b2,
    const float* __restrict__ W3, const float* __restrict__ b3,
    float* __restrict__ out, u64* __restrict__ bits, float* __restrict__ dinv,
    unsigned char* __restrict__ masks, unsigned short* __restrict__ Yt,
    float* __restrict__ H, u32* __restrict__ ctr) {
  __shared__ __align__(16) SMem sm;
  int blk = blockIdx.x;

  ph_masks(masks, blk);
  ph_bits(adj, bits, dinv, blk, sm);
  gridbar(ctr + 0);

  ph_xw(x, W1, dinv, Yt, blk, sm);
  gridbar(ctr + 1);
  ph_spmm(bits, Yt, dinv, b1, masks, H, blk, 1, sm);
  gridbar(ctr + 2);

  ph_xw(H, W2, dinv, Yt, blk, sm);
  gridbar(ctr + 3);
  ph_spmm(bits, Yt, dinv, b2, masks + TOT, H, blk, 1, sm);
  gridbar(ctr + 4);

  ph_xw(H, W3, dinv, Yt, blk, sm);
  gridbar(ctr + 5);
  ph_spmm(bits, Yt, dinv, b3, (const unsigned char*)0, out, blk, 0, sm);
}

// ---------------- launch ----------------
extern "C" void kernel_launch(void* const* d_in, const int* in_sizes, int n_in,
                              void* d_out, int out_size, void* d_ws, size_t ws_size,
                              hipStream_t stream) {
  const float* x  = (const float*)d_in[0];
  const int*   adj= (const int*)d_in[1];
  const float* W1 = (const float*)d_in[2];
  const float* b1 = (const float*)d_in[3];
  const float* W2 = (const float*)d_in[4];
  const float* b2 = (const float*)d_in[5];
  const float* W3 = (const float*)d_in[6];
  const float* b3 = (const float*)d_in[7];
  float* out = (float*)d_out;
  char* ws = (char*)d_ws;

  u64*            bits  = (u64*)(ws);                         // 8,388,608 B
  float*          dinv  = (float*)(ws + 8388608);             //    65,536 B
  unsigned char*  masks = (unsigned char*)(ws + 8454144);     // 2,097,152 B
  unsigned short* Yt    = (unsigned short*)(ws + 10551296);   // 2,097,152 B
  float*          H     = (float*)(ws + 12648448);            // 4,194,304 B
  u32*            ctr   = (u32*)(ws + 16842752);              //        32 B

  k_init<<<1, 64, 0, stream>>>(ctr);
  k_fused<<<GRID, 256, 0, stream>>>(x, adj, W1, b1, W2, b2, W3, b3,
                                    out, bits, dinv, masks, Yt, H, ctr);
}

// Round 4
// 519.036 us; speedup vs baseline: 1.3441x; 1.3441x over previous
//
#include <hip/hip_runtime.h>
#include <math.h>

#define Bsz 4
#define Nn  4096
#define Dd  64
#define TOT (Bsz*Nn*Dd)          // 1048576
#define GRID 512

typedef unsigned int u32;
typedef unsigned long long u64;
typedef unsigned short u16;
typedef short short8 __attribute__((ext_vector_type(8)));
typedef float f32x4 __attribute__((ext_vector_type(4)));

// ---------------- helpers ----------------
__device__ __forceinline__ u16 bf16_of(float x) {
  u32 u = __float_as_uint(x);
  u32 r = (u + 0x7FFFu + ((u >> 16) & 1u)) >> 16;   // RNE
  return (u16)r;
}
__device__ __forceinline__ u32 pack2(float a, float b) {
  return (u32)bf16_of(a) | ((u32)bf16_of(b) << 16);
}
__device__ __forceinline__ void gll16(const void* g, void* l) {
  __builtin_amdgcn_global_load_lds((const __attribute__((address_space(1))) void*)g,
                                   (__attribute__((address_space(3))) void*)l, 16, 0, 0);
}

// Threefry-2x32 (exact JAX rotation/key schedule; partitionable mode verified R1)
__device__ __forceinline__ void tf(u32 k0, u32 k1, u32 x0, u32 x1, u32& y0, u32& y1) {
  u32 ks2 = k0 ^ k1 ^ 0x1BD11BDAu;
  x0 += k0; x1 += k1;
#define TFR(r) { x0 += x1; x1 = (x1 << (r)) | (x1 >> (32 - (r))); x1 ^= x0; }
  TFR(13) TFR(15) TFR(26) TFR(6)
  x0 += k1; x1 += ks2 + 1u;
  TFR(17) TFR(29) TFR(16) TFR(24)
  x0 += ks2; x1 += k0 + 2u;
  TFR(13) TFR(15) TFR(26) TFR(6)
  x0 += k0; x1 += k1 + 3u;
  TFR(17) TFR(29) TFR(16) TFR(24)
  x0 += k1; x1 += ks2 + 4u;
  TFR(13) TFR(15) TFR(26) TFR(6)
  x0 += ks2; x1 += k0 + 5u;
#undef TFR
  y0 = x0; y1 = x1;
}

// bit->bf16 {0,1} expansion (tau-compensated, verified R1/R2)
__device__ __forceinline__ short8 expand_byte(u32 byte) {
  u32 lo = byte & 15u, hi = (byte >> 4) & 15u;
  u32 s0 = (lo * 0x00204081u) & 0x01010101u;
  u32 s1 = (hi * 0x00204081u) & 0x01010101u;
  union { u32 u[4]; short8 v; } r;
  r.u[0] = (s0 & 0x00010001u) * 0x3F80u;
  r.u[1] = ((s0 >> 8) & 0x00010001u) * 0x3F80u;
  r.u[2] = (s1 & 0x00010001u) * 0x3F80u;
  r.u[3] = ((s1 >> 8) & 0x00010001u) * 0x3F80u;
  return r.v;
}
// bit->0xFFFF mask expansion (for ANDing with bf16 dinv_j table)
__device__ __forceinline__ short8 expand_mask(u32 byte) {
  u32 lo = byte & 15u, hi = (byte >> 4) & 15u;
  u32 s0 = (lo * 0x00204081u) & 0x01010101u;
  u32 s1 = (hi * 0x00204081u) & 0x01010101u;
  union { u32 u[4]; short8 v; } r;
  r.u[0] = (s0 & 0x00010001u) * 0xFFFFu;
  r.u[1] = ((s0 >> 8) & 0x00010001u) * 0xFFFFu;
  r.u[2] = (s1 & 0x00010001u) * 0xFFFFu;
  r.u[3] = ((s1 >> 8) & 0x00010001u) * 0xFFFFu;
  return r.v;
}

// ---------------- shared memory union (54.9 KB -> 2 blocks/CU) ----------------
union SMem {
  struct {
    u16 Zt[64 * 256];      // 32768 B  Z tile (swizzled)
    u64 Bl[32][5];         // 1280 B   bits, padded stride 40B (kills 4-way b64 conflict)
    u16 dv[4096];          // 8192 B   bf16 dinv_j table (layer 0 only)
    u16 Wt[64][72];        // 9216 B   next-layer W^T
    u16 Xl[32][72];        // 4608 B   H tile (C-layout -> A-layout round trip)
    float dl[32];          // 128 B    fp32 dinv for this block's rows
  } sp;
  struct { u16 Xl[32][72]; u16 Wt[64][72]; } xw;
  struct { int cnt[32][4]; } bt;
};

// ---------------- two-level grid barrier ----------------
// Arrivals: 64 cachelines (128B stride), 8 blocks/line. Block 0 wave 0 polls all
// 64 lines wave-parallel, butterfly-sums, release-stores per-phase flag.
// Followers poll the flag read-only. Monotone counters (no reset; k_init zeroes).
__device__ __forceinline__ u32 wave_sum(u32 v) {
  v += __shfl_xor(v, 1, 64);  v += __shfl_xor(v, 2, 64);
  v += __shfl_xor(v, 4, 64);  v += __shfl_xor(v, 8, 64);
  v += __shfl_xor(v, 16, 64); v += __shfl_xor(v, 32, 64);
  return v;
}
__device__ void gridbar(u32* ctr, u32* flg, u32 phase) {
  __syncthreads();
  int tid = threadIdx.x;
  if (tid == 0) {
    __builtin_amdgcn_fence(__ATOMIC_RELEASE, "agent");
    __hip_atomic_fetch_add(ctr + (blockIdx.x & 63) * 32, 1u,
                           __ATOMIC_RELAXED, __HIP_MEMORY_SCOPE_AGENT);
  }
  if (blockIdx.x == 0) {
    if (tid < 64) {
      u32 target = (u32)GRID * (phase + 1u);
      for (;;) {
        u32 v = __hip_atomic_load(ctr + tid * 32, __ATOMIC_RELAXED,
                                  __HIP_MEMORY_SCOPE_AGENT);
        if (wave_sum(v) >= target) break;
        __builtin_amdgcn_s_sleep(4);
      }
      if (tid == 0) {
        __builtin_amdgcn_fence(__ATOMIC_ACQUIRE, "agent");
        __hip_atomic_store(flg + phase * 32, 1u, __ATOMIC_RELEASE,
                           __HIP_MEMORY_SCOPE_AGENT);
      }
    }
  } else {
    if (tid == 0) {
      while (__hip_atomic_load(flg + phase * 32, __ATOMIC_RELAXED,
                               __HIP_MEMORY_SCOPE_AGENT) == 0u)
        __builtin_amdgcn_s_sleep(8);
      __builtin_amdgcn_fence(__ATOMIC_ACQUIRE, "agent");
    }
  }
  __syncthreads();
}

// ---------------- phase: Yt1 = swizzled-T(x @ W1), UNSCALED (pre-barrier) ----
__device__ void ph_xw1(const float* __restrict__ X, const float* __restrict__ W,
                       u16* __restrict__ Yt, int blk, SMem& sm) {
  int tid = threadIdx.x;
  int gr0 = blk * 32;
#pragma unroll
  for (int it = 0; it < 4; ++it) {
    int p = it * 256 + tid;
    int r = p >> 5, c2 = (p & 31) * 2;
    const float* s2 = X + (size_t)(gr0 + r) * Dd + c2;
    *(u32*)&sm.xw.Xl[r][c2] = pack2(s2[0], s2[1]);
  }
#pragma unroll
  for (int it = 0; it < 16; ++it) {
    int e = it * 256 + tid;
    sm.xw.Wt[e & 63][e >> 6] = bf16_of(W[e]);
  }
  __syncthreads();
  int lane = tid & 63, wv = tid >> 6, q = lane >> 4, ln = lane & 15;
  int s = wv & 1, tp = wv >> 1;
  f32x4 acc[2];
#pragma unroll
  for (int tt = 0; tt < 2; ++tt) { acc[tt][0]=0.f; acc[tt][1]=0.f; acc[tt][2]=0.f; acc[tt][3]=0.f; }
#pragma unroll
  for (int ks = 0; ks < 2; ++ks) {
    short8 a = *(short8*)&sm.xw.Xl[s * 16 + ln][ks * 32 + q * 8];
#pragma unroll
    for (int tt = 0; tt < 2; ++tt) {
      short8 w8 = *(short8*)&sm.xw.Wt[(tp * 2 + tt) * 16 + ln][ks * 32 + q * 8];
      acc[tt] = __builtin_amdgcn_mfma_f32_16x16x32_bf16(a, w8, acc[tt], 0, 0, 0);
    }
  }
  int b = gr0 >> 12, i0 = gr0 & (Nn - 1);
#pragma unroll
  for (int tt = 0; tt < 2; ++tt) {
    int d = (tp * 2 + tt) * 16 + ln;
    int j0 = i0 + s * 16 + q * 4;
    u16 h[4];
#pragma unroll
    for (int r = 0; r < 4; ++r) h[r] = bf16_of(acc[tt][r]);
    int byte0 = (2 * j0) & 511, blk2 = (2 * j0) >> 9;
    size_t off = ((size_t)b * 64 + d) * (Nn * 2) + ((size_t)blk2 << 9)
               + (size_t)(byte0 ^ ((d & 7) << 4));
    uint2 st; st.x = (u32)h[0] | ((u32)h[1] << 16); st.y = (u32)h[2] | ((u32)h[3] << 16);
    *(uint2*)((char*)Yt + off) = st;
  }
}

// ---------------- phase: adj -> bits + dinv (fp32 + bf16), 32 rows/block ----
__device__ void ph_bits(const int* __restrict__ adj, u64* __restrict__ bits,
                        float* __restrict__ dinv, u16* __restrict__ dinvb,
                        int blk, SMem& sm) {
  __syncthreads();                     // union handoff from ph_xw1
  int tid = threadIdx.x, lane = tid & 63, wv = tid >> 6;
  int gr0 = blk * 32;
#pragma unroll 2
  for (int r = 0; r < 32; ++r) {
    int row = gr0 + r;
    int i = row & (Nn - 1);
    const int4* rp = (const int4*)(adj + (size_t)row * Nn + tid * 16);
    int4 a0 = rp[0], a1 = rp[1], a2 = rp[2], a3 = rp[3];
    u32 v = 0;
    v |= (a0.x != 0) ? (1u << 0) : 0u;  v |= (a0.y != 0) ? (1u << 2) : 0u;
    v |= (a0.z != 0) ? (1u << 1) : 0u;  v |= (a0.w != 0) ? (1u << 3) : 0u;
    v |= (a1.x != 0) ? (1u << 4) : 0u;  v |= (a1.y != 0) ? (1u << 6) : 0u;
    v |= (a1.z != 0) ? (1u << 5) : 0u;  v |= (a1.w != 0) ? (1u << 7) : 0u;
    v |= (a2.x != 0) ? (1u << 8) : 0u;  v |= (a2.y != 0) ? (1u << 10) : 0u;
    v |= (a2.z != 0) ? (1u << 9) : 0u;  v |= (a2.w != 0) ? (1u << 11) : 0u;
    v |= (a3.x != 0) ? (1u << 12) : 0u; v |= (a3.y != 0) ? (1u << 14) : 0u;
    v |= (a3.z != 0) ? (1u << 13) : 0u; v |= (a3.w != 0) ? (1u << 15) : 0u;
    if ((i >> 4) == tid) {             // self-loop column in my 16
      int e = i & 15, e7 = e & 7;
      int m = ((e7 ^ (e7 >> 1)) & 1);
      v |= 1u << ((e & 8) + (e7 ^ (m * 3)));
    }
    ((u16*)bits)[(size_t)row * 256 + tid] = (u16)v;
    int c = __popc(v);
    c += __shfl_down(c, 32, 64); c += __shfl_down(c, 16, 64);
    c += __shfl_down(c, 8, 64);  c += __shfl_down(c, 4, 64);
    c += __shfl_down(c, 2, 64);  c += __shfl_down(c, 1, 64);
    if (lane == 0) sm.bt.cnt[r][wv] = c;
  }
  __syncthreads();
  if (tid < 32) {
    int deg = sm.bt.cnt[tid][0] + sm.bt.cnt[tid][1] + sm.bt.cnt[tid][2] + sm.bt.cnt[tid][3];
    float dvf = (float)(1.0 / sqrt((double)deg));
    dinv[gr0 + tid] = dvf;
    dinvb[gr0 + tid] = bf16_of(dvf);
  }
}

// ---------------- phase: one GCN layer, fully fused ----------------
// S = A_bin @ Zt  (layer 0: af = mask & bf16(dinv_j); layers 1,2: Zt pre-scaled)
// epi: v = S*dinv_i + bias [+ ELU + inline-threefry dropout]
// layers 0,1: H -> LDS -> H @ Wnext -> Yt_out (scaled by dinv_i, swizzled)
// layer 2:    v -> out (fp32)
__device__ void ph_layer(const u64* __restrict__ bits, const u16* __restrict__ YtIn,
                         const float* __restrict__ dinv, const u16* __restrict__ dinvb,
                         const float* __restrict__ bias, const float* __restrict__ Wn,
                         u16* __restrict__ YtOut, float* __restrict__ outG,
                         int layer, u32 ka, u32 kb, int blk, SMem& sm) {
  int tid = threadIdx.x, lane = tid & 63, wv = tid >> 6;
  int q = lane >> 4, ln = lane & 15;
  int s = wv & 1, tp = wv >> 1;
  int gr0 = blk * 32, b = gr0 >> 12, i0 = gr0 & (Nn - 1);

  if (tid < 32) sm.sp.dl[tid] = dinv[gr0 + tid];
  if (layer == 0) {                   // stage bf16 dinv_j table for this batch (8 KB)
    const uint4* src = (const uint4*)(dinvb + (size_t)b * Nn);
    uint4* dst = (uint4*)sm.sp.dv;
    dst[tid] = src[tid];
    dst[tid + 256] = src[tid + 256];
  }
  if (Wn) {                           // stage next-layer W^T
#pragma unroll
    for (int it = 0; it < 16; ++it) {
      int e = it * 256 + tid;
      sm.sp.Wt[e & 63][e >> 6] = bf16_of(Wn[e]);
    }
  }

  f32x4 acc[2];
#pragma unroll
  for (int tt = 0; tt < 2; ++tt) { acc[tt][0]=0.f; acc[tt][1]=0.f; acc[tt][2]=0.f; acc[tt][3]=0.f; }

  const char* ytp = (const char*)YtIn + (size_t)b * 64 * (Nn * 2);
  const char* btp = (const char*)bits + ((size_t)b * Nn + i0) * 512;

  for (int it = 0; it < 16; ++it) {
    __syncthreads();
#pragma unroll
    for (int qq = 0; qq < 8; ++qq) {  // Zt: 32 KB
      int c = wv * 8 + qq;
      int d = c * 2 + (lane >> 5);
      const char* g = ytp + (size_t)d * (Nn * 2) + ((size_t)it << 9) + (size_t)(lane & 31) * 16;
      gll16(g, (char*)sm.sp.Zt + (size_t)c * 1024);
    }
    if (wv == 0) {                    // bits: 1 KB into padded Bl (VGPR path)
      int row = lane >> 1, half = lane & 1;
      uint4 t = *(const uint4*)(btp + (size_t)row * 512 + (size_t)it * 32 + (size_t)half * 16);
      *(uint4*)((char*)sm.sp.Bl + (size_t)row * 40 + (size_t)half * 16) = t;
    }
    __builtin_amdgcn_s_waitcnt(0);
    __syncthreads();

    u64 wd = 0;
#pragma unroll
    for (int kk = 0; kk < 8; ++kk) {
      if ((kk & 1) == 0) wd = sm.sp.Bl[s * 16 + ln][kk >> 1];
      u32 byte = (u32)(wd >> (8 * (4 * (kk & 1) + q))) & 0xFFu;
      short8 af;
      if (layer == 0) {
        short8 m8 = expand_mask(byte);
        short8 d8 = *(short8*)((char*)sm.sp.dv +
                    ((size_t)it * 512 + (size_t)(kk >> 1) * 128 + (size_t)(4 * (kk & 1) + q) * 16));
        union { u32 u[4]; short8 v; } A, B, C;
        A.v = m8; B.v = d8;
        C.u[0] = A.u[0] & B.u[0]; C.u[1] = A.u[1] & B.u[1];
        C.u[2] = A.u[2] & B.u[2]; C.u[3] = A.u[3] & B.u[3];
        af = C.v;
      } else {
        af = expand_byte(byte);
      }
#pragma unroll
      for (int tt = 0; tt < 2; ++tt) {
        int d = (tp * 2 + tt) * 16 + ln;
        int off = ((kk * 64 + q * 16) ^ ((d & 7) << 4)) + d * 512;
        short8 bfr = *(short8*)((char*)sm.sp.Zt + off);
        acc[tt] = __builtin_amdgcn_mfma_f32_16x16x32_bf16(af, bfr, acc[tt], 0, 0, 0);
      }
    }
  }

  // epilogue: dinv_i scale + bias (+ ELU + inline JAX dropout), H -> LDS or out
#pragma unroll
  for (int tt = 0; tt < 2; ++tt) {
    int d = (tp * 2 + tt) * 16 + ln;
    float bv = bias[d];
#pragma unroll
    for (int r = 0; r < 4; ++r) {
      int rl = s * 16 + q * 4 + r;
      int grow = gr0 + rl;
      float v = acc[tt][r] * sm.sp.dl[rl] + bv;
      if (layer < 2) {
        float e = v > 0.f ? v : expm1f(v);
        u32 f = (u32)grow * 64u + (u32)d;
        u32 h0, h1; tf(ka, kb, 0u, f, h0, h1);
        u32 rb = h0 ^ h1;
        float u = __uint_as_float((rb >> 9) | 0x3F800000u) - 1.0f;
        v = (u < 0.8f) ? e * 1.25f : 0.f;     // /0.8 == *1.25 exact
        sm.sp.Xl[rl][d] = bf16_of(v);
      } else {
        outG[(size_t)grow * 64 + d] = v;
      }
    }
  }

  if (Wn) {                           // fused H @ Wnext -> Yt_out (dinv_i-scaled)
    __syncthreads();
    f32x4 ya[2];
#pragma unroll
    for (int tt = 0; tt < 2; ++tt) { ya[tt][0]=0.f; ya[tt][1]=0.f; ya[tt][2]=0.f; ya[tt][3]=0.f; }
#pragma unroll
    for (int ks = 0; ks < 2; ++ks) {
      short8 a = *(short8*)&sm.sp.Xl[s * 16 + ln][ks * 32 + q * 8];
#pragma unroll
      for (int tt = 0; tt < 2; ++tt) {
        short8 w8 = *(short8*)&sm.sp.Wt[(tp * 2 + tt) * 16 + ln][ks * 32 + q * 8];
        ya[tt] = __builtin_amdgcn_mfma_f32_16x16x32_bf16(a, w8, ya[tt], 0, 0, 0);
      }
    }
#pragma unroll
    for (int tt = 0; tt < 2; ++tt) {
      int d = (tp * 2 + tt) * 16 + ln;
      int j0 = i0 + s * 16 + q * 4;
      u16 h[4];
#pragma unroll
      for (int r = 0; r < 4; ++r) h[r] = bf16_of(ya[tt][r] * sm.sp.dl[s * 16 + q * 4 + r]);
      int byte0 = (2 * j0) & 511, blk2 = (2 * j0) >> 9;
      size_t off = ((size_t)b * 64 + d) * (Nn * 2) + ((size_t)blk2 << 9)
                 + (size_t)(byte0 ^ ((d & 7) << 4));
      uint2 st; st.x = (u32)h[0] | ((u32)h[1] << 16); st.y = (u32)h[2] | ((u32)h[3] << 16);
      *(uint2*)((char*)YtOut + off) = st;
    }
  }
}

// ---------------- kernels ----------------
__global__ void k_init(u32* z) {
  int t = threadIdx.x;
  for (int i = t; i < 2304; i += 256) z[i] = 0u;   // 64 arrive lines + 8 flag lines
}

__global__ __launch_bounds__(256, 2) void k_fused(
    const float* __restrict__ x, const int* __restrict__ adj,
    const float* __restrict__ W1, const float* __restrict__ b1,
    const float* __restrict__ W2, const float* __restrict__ b2,
    const float* __restrict__ W3, const float* __restrict__ b3,
    float* __restrict__ out, u64* __restrict__ bits, float* __restrict__ dinv,
    u16* __restrict__ dinvb, u16* __restrict__ YtA, u16* __restrict__ YtB,
    u32* __restrict__ ctr) {
  __shared__ __align__(16) SMem sm;
  int blk = blockIdx.x;
  u32* flg = ctr + 64 * 32;
  u32 k1a, k1b, k2a, k2b;               // split(key(42)), partitionable (R1-verified)
  tf(0u, 42u, 0u, 0u, k1a, k1b);
  tf(0u, 42u, 0u, 1u, k2a, k2b);

  ph_xw1(x, W1, YtA, blk, sm);          // unscaled (dinv not ready yet)
  ph_bits(adj, bits, dinv, dinvb, blk, sm);
  gridbar(ctr, flg, 0);

  ph_layer(bits, YtA, dinv, dinvb, b1, W2, YtB, nullptr, 0, k1a, k1b, blk, sm);
  gridbar(ctr, flg, 1);

  ph_layer(bits, YtB, dinv, dinvb, b2, W3, YtA, nullptr, 1, k2a, k2b, blk, sm);
  gridbar(ctr, flg, 2);

  ph_layer(bits, YtA, dinv, dinvb, b3, nullptr, nullptr, out, 2, 0u, 0u, blk, sm);
}

// ---------------- launch ----------------
extern "C" void kernel_launch(void* const* d_in, const int* in_sizes, int n_in,
                              void* d_out, int out_size, void* d_ws, size_t ws_size,
                              hipStream_t stream) {
  const float* x  = (const float*)d_in[0];
  const int*   adj= (const int*)d_in[1];
  const float* W1 = (const float*)d_in[2];
  const float* b1 = (const float*)d_in[3];
  const float* W2 = (const float*)d_in[4];
  const float* b2 = (const float*)d_in[5];
  const float* W3 = (const float*)d_in[6];
  const float* b3 = (const float*)d_in[7];
  float* out = (float*)d_out;
  char* ws = (char*)d_ws;

  u64*   bits  = (u64*)(ws);                    // 8,388,608 B
  float* dinv  = (float*)(ws + 8388608);        //    65,536 B
  u16*   dinvb = (u16*)(ws + 8454144);          //    32,768 B
  u16*   YtA   = (u16*)(ws + 8486912);          // 2,097,152 B
  u16*   YtB   = (u16*)(ws + 10584064);         // 2,097,152 B
  u32*   ctr   = (u32*)(ws + 12681216);         //     9,216 B

  k_init<<<1, 256, 0, stream>>>(ctr);
  k_fused<<<GRID, 256, 0, stream>>>(x, adj, W1, b1, W2, b2, W3, b3,
                                    out, bits, dinv, dinvb, YtA, YtB, ctr);
}